// Round 6
// baseline (595.526 us; speedup 1.0000x reference)
//
#include <hip/hip_runtime.h>

// ---------------------------------------------------------------------------
// BertAttention (relative_key_query) on MI355X. FP32 I/O, bf16 MFMA compute.
// B=8 S=1024 E=1024 H=16 D=64 M=1024
// R6: GEMM 128x128 (32 MFMA/wave-kstep, pure b128 staging); attn: global
// pre-transposed V + pre-converted bf16 dist (direct-copy staging), circular
// Gq (half the rel-q MFMAs/writes per ktile).
// ---------------------------------------------------------------------------

typedef unsigned short u16;
typedef unsigned int u32;
typedef unsigned long long u64;
typedef __bf16 bf16x8 __attribute__((ext_vector_type(8)));
typedef float  f32x4  __attribute__((ext_vector_type(4)));
typedef int    i32x4  __attribute__((ext_vector_type(4)));

__device__ __forceinline__ float b2f(u16 u) {
  union { u32 i; float f; } x;
  x.i = ((u32)u) << 16;
  return x.f;
}
__device__ __forceinline__ u16 f2b_manual(float f) {
  union { float f; u32 u; } x;
  x.f = f;
  return (u16)((x.u + 0x7FFFu + ((x.u >> 16) & 1u)) >> 16);
}
#if __has_builtin(__builtin_amdgcn_cvt_pk_bf16_f32)
typedef __bf16 bf16x2 __attribute__((ext_vector_type(2)));
__device__ __forceinline__ u32 cvt2(float a, float b) {
  union { bf16x2 v; u32 u; } x;
  x.v = __builtin_amdgcn_cvt_pk_bf16_f32(a, b);
  return x.u;
}
#else
__device__ __forceinline__ u32 cvt2(float a, float b) {
  return (u32)f2b_manual(a) | ((u32)f2b_manual(b) << 16);
}
#endif
__device__ __forceinline__ u16 f2b(float f) { return (u16)(cvt2(f, f) & 0xffffu); }

union LdU { i32x4 i4; bf16x8 b8; };
__device__ __forceinline__ bf16x8 ldb8(const u16* p) {
  LdU u; u.i4 = *(const i32x4*)p; return u.b8;
}
__device__ __forceinline__ void pack8(u16* dst, const float* src) {
  f32x4 lo = *(const f32x4*)src, hi = *(const f32x4*)(src + 4);
  i32x4 v;
  v.x = (int)cvt2(lo.x, lo.y); v.y = (int)cvt2(lo.z, lo.w);
  v.z = (int)cvt2(hi.x, hi.y); v.w = (int)cvt2(hi.z, hi.w);
  *(i32x4*)dst = v;
}
#define MFMA16(a, b, c) __builtin_amdgcn_mfma_f32_16x16x32_bf16((a), (b), (c), 0, 0, 0)

template <int C>
__device__ __forceinline__ float dppmov(float x) {
  union { float f; int i; } a, r;
  a.f = x;
  r.i = __builtin_amdgcn_update_dpp(0, a.i, C, 0xF, 0xF, true);
  return r.f;
}
__device__ __forceinline__ float rsum16(float x) {
  x += dppmov<0xB1>(x);   // quad_perm xor1
  x += dppmov<0x4E>(x);   // quad_perm xor2
  x += dppmov<0x141>(x);  // row_half_mirror (^7)
  x += dppmov<0x140>(x);  // row_mirror (^15)
  return x;
}
__device__ __forceinline__ float fexp2(float x) {
#if __has_builtin(__builtin_amdgcn_exp2f)
  return __builtin_amdgcn_exp2f(x);
#else
  return exp2f(x);
#endif
}

// ---------------------------------------------------------------------------
__global__ __launch_bounds__(256) void convX(
    const float* __restrict__ X, u16* __restrict__ Xb) {
  int i = (blockIdx.x * 256 + threadIdx.x) * 8;
  pack8(&Xb[i], &X[i]);
}

__global__ __launch_bounds__(256) void convD(
    const float* __restrict__ dist, u16* __restrict__ distb) {
  int i = (blockIdx.x * 256 + threadIdx.x) * 8;
  if (i < 2047 * 64) pack8(&distb[i], &dist[i]);
}

// convWt: W[1024][1024] fp32 -> Wt[m][k] bf16 (transposed), 64x64 LDS tiles.
__global__ __launch_bounds__(256) void convWt(
    const float* __restrict__ W, u16* __restrict__ Wt) {
  __shared__ float tile[64][65];
  const int tid = threadIdx.x;
  const int k0 = blockIdx.x * 64, m0 = blockIdx.y * 64;
#pragma unroll
  for (int it = 0; it < 4; it++) {
    int row = (tid >> 4) + 16 * it;
    int col = (tid & 15) * 4;
    f32x4 v = *(const f32x4*)&W[(size_t)(k0 + row) * 1024 + m0 + col];
    tile[row][col] = v.x; tile[row][col + 1] = v.y;
    tile[row][col + 2] = v.z; tile[row][col + 3] = v.w;
  }
  __syncthreads();
#pragma unroll
  for (int it = 0; it < 4; it++) {
    int mr = (tid >> 4) + 16 * it;
    int kc = (tid & 15) * 4;
    u32 w0 = cvt2(tile[kc][mr], tile[kc + 1][mr]);
    u32 w1 = cvt2(tile[kc + 2][mr], tile[kc + 3][mr]);
    *(u64*)&Wt[(size_t)(m0 + mr) * 1024 + k0 + kc] = (u64)w0 | ((u64)w1 << 32);
  }
}

// transV: Vw[b*1024+s][h*64+d] bf16 -> Vt[bh][d][s] bf16.
__global__ __launch_bounds__(256) void transV(
    const u16* __restrict__ V, u16* __restrict__ Vt) {
  __shared__ u16 tile[64][72];
  const int tid = threadIdx.x;
  const int bh = blockIdx.y, b = bh >> 4, h = bh & 15;
  const int s0 = blockIdx.x << 6;
  const u16* Vb = V + (size_t)(b * 1024) * 1024 + h * 64;
  {
    int rp = tid >> 3, a = tid & 7;  // rp: s-row pair, a: d-group
    const u16* src = &Vb[(size_t)(s0 + 2 * rp) * 1024 + a * 8];
    i32x4 va = *(const i32x4*)src;
    i32x4 vb2 = *(const i32x4*)(src + 1024);
    u16 ta[8] __attribute__((aligned(16)));
    u16 tb[8] __attribute__((aligned(16)));
    *(i32x4*)ta = va; *(i32x4*)tb = vb2;
    int colb = ((((rp >> 2) ^ a) << 3) | ((2 * rp) & 7));
#pragma unroll
    for (int j = 0; j < 8; j++)
      *(u32*)&tile[a * 8 + j][colb] = (u32)ta[j] | ((u32)tb[j] << 16);
  }
  __syncthreads();
  int d = tid >> 2, cc = tid & 3;
  int sw = (d >> 3) & 7;
  i32x4 lo = *(const i32x4*)&tile[d][((2 * cc) ^ sw) << 3];
  i32x4 hi = *(const i32x4*)&tile[d][((2 * cc + 1) ^ sw) << 3];
  u16* dst = Vt + ((size_t)bh * 64 + d) * 1024 + s0 + cc * 16;
  *(i32x4*)dst = lo;
  *(i32x4*)(dst + 8) = hi;
}

// ---------------------------------------------------------------------------
// GEMM: out[N,M] = A[N,K] @ Wt^T + bias (+ residual). 128x128 tile, BK=64,
// 4 waves x (32 rows x 128 cols). Pure-bf16 b128 staging both operands.
// ---------------------------------------------------------------------------
template <int RESID, int OUTF32>
__global__ __launch_bounds__(256) void gemm_bb(
    const u16* __restrict__ A, const u16* __restrict__ Wt,
    const float* __restrict__ bias, const float* __restrict__ resid,
    float* __restrict__ outF, u16* __restrict__ outB, int N, int K, int M) {
  __shared__ u16 sA[128][72];
  __shared__ u16 sW[128][72];  // sW[n][k] = Wt[m0+n][k0+k]

  const int tid = threadIdx.x;
  const int lane = tid & 63, w = tid >> 6;
  const int quad = lane >> 4, lb = lane & 15;
  const int m0 = blockIdx.x * 128, n0 = blockIdx.y * 128;

  f32x4 acc[2][8] = {};

  for (int k0 = 0; k0 < K; k0 += 64) {
#pragma unroll
    for (int ch = tid; ch < 1024; ch += 256) {
      int r = ch >> 3, c8 = (ch & 7) << 3;
      *(i32x4*)&sA[r][c8] = *(const i32x4*)&A[(size_t)(n0 + r) * K + k0 + c8];
      *(i32x4*)&sW[r][c8] = *(const i32x4*)&Wt[(size_t)(m0 + r) * K + k0 + c8];
    }
    __syncthreads();

    const int r0 = 32 * w + lb;
    bf16x8 a00 = ldb8(&sA[r0][quad * 8]);
    bf16x8 a01 = ldb8(&sA[r0][32 + quad * 8]);
    bf16x8 a10 = ldb8(&sA[r0 + 16][quad * 8]);
    bf16x8 a11 = ldb8(&sA[r0 + 16][32 + quad * 8]);
#pragma unroll
    for (int t = 0; t < 8; t++) {
      int n = 16 * t + lb;
      bf16x8 b0 = ldb8(&sW[n][quad * 8]);
      bf16x8 b1 = ldb8(&sW[n][32 + quad * 8]);
      acc[0][t] = MFMA16(a00, b0, acc[0][t]);
      acc[0][t] = MFMA16(a01, b1, acc[0][t]);
      acc[1][t] = MFMA16(a10, b0, acc[1][t]);
      acc[1][t] = MFMA16(a11, b1, acc[1][t]);
    }
    __syncthreads();
  }

#pragma unroll
  for (int half = 0; half < 2; half++)
#pragma unroll
    for (int t = 0; t < 8; t++) {
      int col = m0 + 16 * t + lb;
      float bv = bias[col];
#pragma unroll
      for (int i = 0; i < 4; i++) {
        int rowg = n0 + 32 * w + 16 * half + quad * 4 + i;
        float v = acc[half][t][i] + bv;
        if (RESID) v += resid[(size_t)rowg * M + col];
        if (OUTF32) outF[(size_t)rowg * M + col] = v;
        else        outB[(size_t)rowg * M + col] = f2b(v);
      }
    }
}

// ---------------------------------------------------------------------------
// Fused attention: one block = (b, h, 64 q-rows), 16 k-tiles of 64.
// Rel bias Gq/Gk via MFMA, stored transposed at circular phys rows
// (phys = logical ^ xorv, shared scheme with sP). Gq persists across ktiles
// (only 64 new window cols/ktile). V staged from pre-transposed global Vt;
// dist staged from pre-converted bf16. Fixed-max exp2 softmax.
// ---------------------------------------------------------------------------
__global__ __launch_bounds__(256) void attn(
    const u16* __restrict__ Q, const u16* __restrict__ Kv,
    const u16* __restrict__ Vt, const u16* __restrict__ distb,
    u16* __restrict__ ctx) {
  __shared__ u16 sQ[64][72];
  __shared__ u16 sK[64][72];      // probs overlay after barrier B
  __shared__ u16 sVt[64][72];     // V^T [d][r], direct-copied
  __shared__ u16 sP[128][72];     // dist window, circular
  __shared__ u16 sGqT[128][66];   // GqT[phys][rl], circular w/ sP scheme
  __shared__ u16 sGkT[128][68];   // GkT[phys][cl], rewritten each ktile

  const int tid = threadIdx.x;
  const int lane = tid & 63, w = tid >> 6;
  const int quad = lane >> 4, lb = lane & 15;
  const int bh = blockIdx.y, b = bh >> 4, h = bh & 15;
  const int q0 = blockIdx.x << 6;
  const int S = 1024, E = 1024;
  const u16* Qb = Q  + (size_t)(b * S) * E + h * 64;
  const u16* Kb = Kv + (size_t)(b * S) * E + h * 64;
  const u16* Vtb = Vt + (size_t)bh * 64 * 1024;

  for (int ch = tid; ch < 512; ch += 256) {
    int r = ch >> 3, c8 = (ch & 7) << 3;
    *(i32x4*)&sQ[r][c8] = *(const i32x4*)&Qb[(size_t)(q0 + r) * E + c8];
  }
  __syncthreads();

  const int row = 16 * w + lb;
  bf16x8 aq0 = ldb8(&sQ[row][quad * 8]);
  bf16x8 aq1 = ldb8(&sQ[row][32 + quad * 8]);

  f32x4 accO[4] = {};
  float l_i[4] = {0.f, 0.f, 0.f, 0.f};
  const float C2 = 0.125f * 1.44269504f;

  for (int kt = 0; kt < 16; kt++) {
    const int r0 = kt << 6;
    const int xorv = (kt & 1) << 6;
    // stage K tile
    for (int ch = tid; ch < 512; ch += 256) {
      int r = ch >> 3, c8 = (ch & 7) << 3;
      *(i32x4*)&sK[r][c8] = *(const i32x4*)&Kb[(size_t)(r0 + r) * E + c8];
    }
    // stage V^T tile: direct b128 copy from Vt[bh][d][r0..r0+64)
    for (int ch = tid; ch < 512; ch += 256) {
      int r = ch >> 3, c8 = (ch & 7) << 3;
      *(i32x4*)&sVt[r][c8] = *(const i32x4*)&Vtb[(size_t)r * 1024 + r0 + c8];
    }
    // stage dist window (bf16, circular): kt=0 all 128 rows, else 64 new
    const int dbase = q0 - r0 + 960;
    if (kt == 0) {
      for (int ch = tid; ch < 1024; ch += 256) {
        int p = ch >> 3, c8 = (ch & 7) << 3;
        int g = dbase + p;
        if (g > 2046) g = 2046;
        *(i32x4*)&sP[p][c8] = *(const i32x4*)&distb[(size_t)g * 64 + c8];
      }
    } else {
      for (int ch = tid; ch < 512; ch += 256) {
        int p = ch >> 3, c8 = (ch & 7) << 3;
        int g = dbase + p;
        *(i32x4*)&sP[p ^ xorv][c8] = *(const i32x4*)&distb[(size_t)g * 64 + c8];
      }
    }
    __syncthreads();  // barrier A

    // --- QK^T ---
    f32x4 accS[4] = {};
#pragma unroll
    for (int t = 0; t < 4; t++) {
      int n = 16 * t + lb;
      bf16x8 b0 = ldb8(&sK[n][quad * 8]);
      bf16x8 b1 = ldb8(&sK[n][32 + quad * 8]);
      accS[t] = MFMA16(aq0, b0, accS[t]);
      accS[t] = MFMA16(aq1, b1, accS[t]);
    }
    // --- rel-bias GEMMs: Gk all 8 u; Gq only new cols (u<4) when kt>0 ---
    bf16x8 ak0 = ldb8(&sK[row][quad * 8]);
    bf16x8 ak1 = ldb8(&sK[row][32 + quad * 8]);
#pragma unroll
    for (int u = 0; u < 8; u++) {
      int prow = (16 * u + lb) ^ xorv;
      bf16x8 p0 = ldb8(&sP[prow][quad * 8]);
      bf16x8 p1 = ldb8(&sP[prow][32 + quad * 8]);
      f32x4 gk = {};
      gk = MFMA16(ak0, p0, gk); gk = MFMA16(ak1, p1, gk);
      u64 kv = (u64)cvt2(gk[0], gk[1]) | ((u64)cvt2(gk[2], gk[3]) << 32);
      *(u64*)&sGkT[prow][16 * w + 4 * quad] = kv;
      if (u < 4 || kt == 0) {
        f32x4 gq = {};
        gq = MFMA16(aq0, p0, gq); gq = MFMA16(aq1, p1, gq);
        *(u32*)&sGqT[prow][16 * w + 4 * quad] = cvt2(gq[0], gq[1]);
        *(u32*)&sGqT[prow][16 * w + 4 * quad + 2] = cvt2(gq[2], gq[3]);
      }
    }
    __syncthreads();  // barrier B

    // --- bias gather + fixed-max softmax (exp2 domain) ---
    float pr[4][4], rsum[4] = {0.f, 0.f, 0.f, 0.f};
#pragma unroll
    for (int t = 0; t < 4; t++) {
#pragma unroll
      for (int i = 0; i < 4; i++) {
        int rl = 16 * w + quad * 4 + i;
        int cl = 16 * t + lb;
        int pc = (rl - cl + 63) ^ xorv;
        float s = accS[t][i] + b2f(sGqT[pc][rl]) + b2f(sGkT[pc][cl]);
        float e = fexp2(s * C2);
        pr[t][i] = e;
        rsum[i] += e;
      }
    }
#pragma unroll
    for (int i = 0; i < 4; i++) l_i[i] += rsum16(rsum[i]);

    // probs -> sK overlay (own-wave rows only)
#pragma unroll
    for (int t = 0; t < 4; t++)
#pragma unroll
      for (int i = 0; i < 4; i++)
        sK[16 * w + quad * 4 + i][16 * t + lb] = f2b(pr[t][i]);

    // --- PV ---
    bf16x8 ap0 = ldb8(&sK[row][quad * 8]);
    bf16x8 ap1 = ldb8(&sK[row][32 + quad * 8]);
#pragma unroll
    for (int t = 0; t < 4; t++) {
      int n = 16 * t + lb;
      bf16x8 v0 = ldb8(&sVt[n][quad * 8]);
      bf16x8 v1 = ldb8(&sVt[n][32 + quad * 8]);
      accO[t] = MFMA16(ap0, v0, accO[t]);
      accO[t] = MFMA16(ap1, v1, accO[t]);
    }
    __syncthreads();  // barrier C
  }

  u16* Cb = ctx + (size_t)(b * S) * E + h * 64;
#pragma unroll
  for (int t = 0; t < 4; t++)
#pragma unroll
    for (int i = 0; i < 4; i++) {
      int rl = 16 * w + quad * 4 + i;
      Cb[(size_t)(q0 + rl) * E + 16 * t + lb] = f2b(accO[t][i] / l_i[i]);
    }
}

// ---------------------------------------------------------------------------
__global__ __launch_bounds__(256) void lnorm(
    const float* __restrict__ Hp, const float* __restrict__ gamma,
    const float* __restrict__ beta, float* __restrict__ out) {
  __shared__ float red[8];
  const int rowb = blockIdx.x, tid = threadIdx.x;
  const float* hr = Hp + (size_t)rowb * 1024;
  f32x4 v = *(const f32x4*)&hr[tid * 4];
  float s = v.x + v.y + v.z + v.w;
  float q = v.x * v.x + v.y * v.y + v.z * v.z + v.w * v.w;
#pragma unroll
  for (int d = 1; d < 64; d <<= 1) {
    s += __shfl_xor(s, d, 64);
    q += __shfl_xor(q, d, 64);
  }
  int w = tid >> 6, lane = tid & 63;
  if (lane == 0) { red[w] = s; red[4 + w] = q; }
  __syncthreads();
  s = red[0] + red[1] + red[2] + red[3];
  q = red[4] + red[5] + red[6] + red[7];
  float mu = s * (1.f / 1024.f);
  float var = q * (1.f / 1024.f) - mu * mu;
  float rstd = rsqrtf(var + 1e-12f);
  float* orow = out + (size_t)rowb * 1024;
  f32x4 o;
#pragma unroll
  for (int j = 0; j < 4; j++) {
    int c = tid * 4 + j;
    o[j] = (v[j] - mu) * rstd * gamma[c] + beta[c];
  }
  *(f32x4*)&orow[tid * 4] = o;
}

// ---------------------------------------------------------------------------
extern "C" void kernel_launch(void* const* d_in, const int* in_sizes, int n_in,
                              void* d_out, int out_size, void* d_ws,
                              size_t ws_size, hipStream_t stream) {
  const float* X    = (const float*)d_in[0];
  const float* Wq   = (const float*)d_in[1];
  const float* bq   = (const float*)d_in[2];
  const float* Wk   = (const float*)d_in[3];
  const float* bk   = (const float*)d_in[4];
  const float* Wv   = (const float*)d_in[5];
  const float* bv   = (const float*)d_in[6];
  const float* dist = (const float*)d_in[7];
  const float* Wo   = (const float*)d_in[8];
  const float* bo   = (const float*)d_in[9];
  const float* gam  = (const float*)d_in[10];
  const float* bet  = (const float*)d_in[11];

  const size_t NE = (size_t)8192 * 1024;
  char* ws = (char*)d_ws;
  u16* Qw = (u16*)(ws);
  u16* Kw = (u16*)(ws + 2 * NE);
  u16* Vw = (u16*)(ws + 4 * NE);
  u16* Cw = (u16*)(ws + 6 * NE);
  float* Hp = (float*)ws;  // fp32 pre-LN, overlays dead Q+K

  // d_out (32 MiB fp32) as scratch until lnorm overwrites it:
  // [0,8): Wt q/k/v/o (2 MiB each). [8, 24.75): Xb bf16, later overlaid by
  // Vt bf16 (Xb dead after QKV GEMMs). [26, 26.25): distb bf16.
  char* ob = (char*)d_out;
  u16* Wtq = (u16*)(ob);
  u16* Wtk = (u16*)(ob + (2u << 20));
  u16* Wtv = (u16*)(ob + (4u << 20));
  u16* Wto = (u16*)(ob + (6u << 20));
  u16* Xb  = (u16*)(ob + (8u << 20));
  u16* Vtg = (u16*)(ob + (8u << 20));   // overlays Xb (disjoint lifetime)
  u16* distb = (u16*)(ob + (26u << 20));

  dim3 bb(256);
  dim3 gw(16, 16);
  convWt<<<gw, bb, 0, stream>>>(Wq, Wtq);
  convWt<<<gw, bb, 0, stream>>>(Wk, Wtk);
  convWt<<<gw, bb, 0, stream>>>(Wv, Wtv);
  convWt<<<gw, bb, 0, stream>>>(Wo, Wto);
  convX<<<dim3(4096), bb, 0, stream>>>(X, Xb);
  convD<<<dim3(64), bb, 0, stream>>>(dist, distb);

  dim3 gg(8, 64);
  gemm_bb<0, 0><<<gg, bb, 0, stream>>>(Xb, Wtq, bq, nullptr, nullptr, Qw, 8192, 1024, 1024);
  gemm_bb<0, 0><<<gg, bb, 0, stream>>>(Xb, Wtk, bk, nullptr, nullptr, Kw, 8192, 1024, 1024);
  gemm_bb<0, 0><<<gg, bb, 0, stream>>>(Xb, Wtv, bv, nullptr, nullptr, Vw, 8192, 1024, 1024);
  transV<<<dim3(16, 128), bb, 0, stream>>>(Vw, Vtg);
  attn<<<dim3(16, 128), bb, 0, stream>>>(Qw, Kw, Vtg, distb, Cw);
  gemm_bb<1, 1><<<gg, bb, 0, stream>>>(Cw, Wto, bo, X, Hp, nullptr, 8192, 1024, 1024);
  lnorm<<<dim3(8192), bb, 0, stream>>>(Hp, gam, bet, (float*)d_out);
}

// Round 7
// 523.183 us; speedup vs baseline: 1.1383x; 1.1383x over previous
//
#include <hip/hip_runtime.h>

// ---------------------------------------------------------------------------
// BertAttention (relative_key_query) on MI355X. FP32 I/O, bf16 MFMA compute.
// B=8 S=1024 E=1024 H=16 D=64 M=1024
// R7: GEMM via global_load_lds (async DMA staging, XOR8-swizzled unpadded
// LDS); attn: unconditional G loop (revert R6 branchy circular-Gq), G arrays
// stride-64 XOR8-swizzled (2-way banks on writes+gather).
// ---------------------------------------------------------------------------

typedef unsigned short u16;
typedef unsigned int u32;
typedef unsigned long long u64;
typedef __bf16 bf16x8 __attribute__((ext_vector_type(8)));
typedef float  f32x4  __attribute__((ext_vector_type(4)));
typedef int    i32x4  __attribute__((ext_vector_type(4)));

__device__ __forceinline__ float b2f(u16 u) {
  union { u32 i; float f; } x;
  x.i = ((u32)u) << 16;
  return x.f;
}
__device__ __forceinline__ u16 f2b_manual(float f) {
  union { float f; u32 u; } x;
  x.f = f;
  return (u16)((x.u + 0x7FFFu + ((x.u >> 16) & 1u)) >> 16);
}
#if __has_builtin(__builtin_amdgcn_cvt_pk_bf16_f32)
typedef __bf16 bf16x2 __attribute__((ext_vector_type(2)));
__device__ __forceinline__ u32 cvt2(float a, float b) {
  union { bf16x2 v; u32 u; } x;
  x.v = __builtin_amdgcn_cvt_pk_bf16_f32(a, b);
  return x.u;
}
#else
__device__ __forceinline__ u32 cvt2(float a, float b) {
  return (u32)f2b_manual(a) | ((u32)f2b_manual(b) << 16);
}
#endif
__device__ __forceinline__ u16 f2b(float f) { return (u16)(cvt2(f, f) & 0xffffu); }

union LdU { i32x4 i4; bf16x8 b8; };
__device__ __forceinline__ bf16x8 ldb8(const u16* p) {
  LdU u; u.i4 = *(const i32x4*)p; return u.b8;
}
__device__ __forceinline__ void pack8(u16* dst, const float* src) {
  f32x4 lo = *(const f32x4*)src, hi = *(const f32x4*)(src + 4);
  i32x4 v;
  v.x = (int)cvt2(lo.x, lo.y); v.y = (int)cvt2(lo.z, lo.w);
  v.z = (int)cvt2(hi.x, hi.y); v.w = (int)cvt2(hi.z, hi.w);
  *(i32x4*)dst = v;
}
#define MFMA16(a, b, c) __builtin_amdgcn_mfma_f32_16x16x32_bf16((a), (b), (c), 0, 0, 0)

template <int C>
__device__ __forceinline__ float dppmov(float x) {
  union { float f; int i; } a, r;
  a.f = x;
  r.i = __builtin_amdgcn_update_dpp(0, a.i, C, 0xF, 0xF, true);
  return r.f;
}
__device__ __forceinline__ float rsum16(float x) {
  x += dppmov<0xB1>(x);   // quad_perm xor1
  x += dppmov<0x4E>(x);   // quad_perm xor2
  x += dppmov<0x141>(x);  // row_half_mirror (^7)
  x += dppmov<0x140>(x);  // row_mirror (^15)
  return x;
}
__device__ __forceinline__ float fexp2(float x) {
#if __has_builtin(__builtin_amdgcn_exp2f)
  return __builtin_amdgcn_exp2f(x);
#else
  return exp2f(x);
#endif
}

// async global->LDS 16B/lane; LDS dest must be wave-uniform base (HW adds
// lane*16). Fallback: manual copy producing identical layout.
#if __has_builtin(__builtin_amdgcn_global_load_lds)
#define HAS_GLDS 1
typedef __attribute__((address_space(3))) u32 as3_u32;
typedef const __attribute__((address_space(1))) u32 as1_u32;
__device__ __forceinline__ void gld16(const u16* g, u16* lds_wave_base) {
  __builtin_amdgcn_global_load_lds(
      (as1_u32*)g, (as3_u32*)(u32)(u64)lds_wave_base, 16, 0, 0);
}
#else
#define HAS_GLDS 0
__device__ __forceinline__ void gld16_fb(const u16* g, u16* lds_wave_base,
                                         int lane) {
  *(i32x4*)(lds_wave_base + lane * 8) = *(const i32x4*)g;
}
#endif

// ---------------------------------------------------------------------------
__global__ __launch_bounds__(256) void convX(
    const float* __restrict__ X, u16* __restrict__ Xb) {
  int i = (blockIdx.x * 256 + threadIdx.x) * 8;
  pack8(&Xb[i], &X[i]);
}

__global__ __launch_bounds__(256) void convD(
    const float* __restrict__ dist, u16* __restrict__ distb) {
  int i = (blockIdx.x * 256 + threadIdx.x) * 8;
  if (i < 2047 * 64) pack8(&distb[i], &dist[i]);
}

// convWt: W[1024][1024] fp32 -> Wt[m][k] bf16 (transposed), 64x64 LDS tiles.
__global__ __launch_bounds__(256) void convWt(
    const float* __restrict__ W, u16* __restrict__ Wt) {
  __shared__ float tile[64][65];
  const int tid = threadIdx.x;
  const int k0 = blockIdx.x * 64, m0 = blockIdx.y * 64;
#pragma unroll
  for (int it = 0; it < 4; it++) {
    int row = (tid >> 4) + 16 * it;
    int col = (tid & 15) * 4;
    f32x4 v = *(const f32x4*)&W[(size_t)(k0 + row) * 1024 + m0 + col];
    tile[row][col] = v.x; tile[row][col + 1] = v.y;
    tile[row][col + 2] = v.z; tile[row][col + 3] = v.w;
  }
  __syncthreads();
#pragma unroll
  for (int it = 0; it < 4; it++) {
    int mr = (tid >> 4) + 16 * it;
    int kc = (tid & 15) * 4;
    u32 w0 = cvt2(tile[kc][mr], tile[kc + 1][mr]);
    u32 w1 = cvt2(tile[kc + 2][mr], tile[kc + 3][mr]);
    *(u64*)&Wt[(size_t)(m0 + mr) * 1024 + k0 + kc] = (u64)w0 | ((u64)w1 << 32);
  }
}

// transV: Vw[b*1024+s][h*64+d] bf16 -> Vt[bh][d][s] bf16.
__global__ __launch_bounds__(256) void transV(
    const u16* __restrict__ V, u16* __restrict__ Vt) {
  __shared__ u16 tile[64][72];
  const int tid = threadIdx.x;
  const int bh = blockIdx.y, b = bh >> 4, h = bh & 15;
  const int s0 = blockIdx.x << 6;
  const u16* Vb = V + (size_t)(b * 1024) * 1024 + h * 64;
  {
    int rp = tid >> 3, a = tid & 7;
    const u16* src = &Vb[(size_t)(s0 + 2 * rp) * 1024 + a * 8];
    i32x4 va = *(const i32x4*)src;
    i32x4 vb2 = *(const i32x4*)(src + 1024);
    u16 ta[8] __attribute__((aligned(16)));
    u16 tb[8] __attribute__((aligned(16)));
    *(i32x4*)ta = va; *(i32x4*)tb = vb2;
    int colb = ((((rp >> 2) ^ a) << 3) | ((2 * rp) & 7));
#pragma unroll
    for (int j = 0; j < 8; j++)
      *(u32*)&tile[a * 8 + j][colb] = (u32)ta[j] | ((u32)tb[j] << 16);
  }
  __syncthreads();
  int d = tid >> 2, cc = tid & 3;
  int sw = (d >> 3) & 7;
  i32x4 lo = *(const i32x4*)&tile[d][((2 * cc) ^ sw) << 3];
  i32x4 hi = *(const i32x4*)&tile[d][((2 * cc + 1) ^ sw) << 3];
  u16* dst = Vt + ((size_t)bh * 64 + d) * 1024 + s0 + cc * 16;
  *(i32x4*)dst = lo;
  *(i32x4*)(dst + 8) = hi;
}

// ---------------------------------------------------------------------------
// GEMM: out[N,M] = A[N,K] @ Wt^T + bias (+ residual). 128x128 tile, BK=64,
// 4 waves x 32x128. Staging via global_load_lds (16B/lane) into unpadded
// [128][64] LDS with XOR8 col-group swizzle applied on the GLOBAL address
// (lane permutation within a 128B window -> coalescing preserved).
// ---------------------------------------------------------------------------
template <int RESID, int OUTF32>
__global__ __launch_bounds__(256) void gemm_bb(
    const u16* __restrict__ A, const u16* __restrict__ Wt,
    const float* __restrict__ bias, const float* __restrict__ resid,
    float* __restrict__ outF, u16* __restrict__ outB, int N, int K, int M) {
  __shared__ u16 sA[128 * 64];
  __shared__ u16 sW[128 * 64];

  const int tid = threadIdx.x;
  const int lane = tid & 63, w = tid >> 6;
  const int quad = lane >> 4, lb = lane & 15;
  const int m0 = blockIdx.x * 128, n0 = blockIdx.y * 128;

  // staging geometry: chunk = 8 rows x 64 cols = 1KB; wave w stages chunks
  // 4w..4w+3. lane -> (srow = lane>>3 within chunk, col-group lane&7).
  const int srow = lane >> 3;
  const int gcol = ((lane & 7) ^ srow) << 3;  // XOR8 swizzle on global side

  f32x4 acc[2][8] = {};

  for (int k0 = 0; k0 < K; k0 += 64) {
#pragma unroll
    for (int j = 0; j < 4; j++) {
      int rb = (4 * w + j) * 8;
      const u16* ga = &A[(size_t)(n0 + rb + srow) * K + k0 + gcol];
      const u16* gw = &Wt[(size_t)(m0 + rb + srow) * K + k0 + gcol];
#if HAS_GLDS
      gld16(ga, &sA[rb * 64]);
      gld16(gw, &sW[rb * 64]);
#else
      gld16_fb(ga, &sA[rb * 64], lane);
      gld16_fb(gw, &sW[rb * 64], lane);
#endif
    }
    __syncthreads();

    const int r0 = 32 * w + lb;
    const int sw0 = r0 & 7;  // (r0+16)&7 == sw0
    bf16x8 a00 = ldb8(&sA[r0 * 64 + ((quad ^ sw0) << 3)]);
    bf16x8 a01 = ldb8(&sA[r0 * 64 + (((4 + quad) ^ sw0) << 3)]);
    bf16x8 a10 = ldb8(&sA[(r0 + 16) * 64 + ((quad ^ sw0) << 3)]);
    bf16x8 a11 = ldb8(&sA[(r0 + 16) * 64 + (((4 + quad) ^ sw0) << 3)]);
#pragma unroll
    for (int t = 0; t < 8; t++) {
      int n = 16 * t + lb;
      int swn = n & 7;
      bf16x8 b0 = ldb8(&sW[n * 64 + ((quad ^ swn) << 3)]);
      bf16x8 b1 = ldb8(&sW[n * 64 + (((4 + quad) ^ swn) << 3)]);
      acc[0][t] = MFMA16(a00, b0, acc[0][t]);
      acc[0][t] = MFMA16(a01, b1, acc[0][t]);
      acc[1][t] = MFMA16(a10, b0, acc[1][t]);
      acc[1][t] = MFMA16(a11, b1, acc[1][t]);
    }
    __syncthreads();
  }

#pragma unroll
  for (int half = 0; half < 2; half++)
#pragma unroll
    for (int t = 0; t < 8; t++) {
      int col = m0 + 16 * t + lb;
      float bv = bias[col];
#pragma unroll
      for (int i = 0; i < 4; i++) {
        int rowg = n0 + 32 * w + 16 * half + quad * 4 + i;
        float v = acc[half][t][i] + bv;
        if (RESID) v += resid[(size_t)rowg * M + col];
        if (OUTF32) outF[(size_t)rowg * M + col] = v;
        else        outB[(size_t)rowg * M + col] = f2b(v);
      }
    }
}

// ---------------------------------------------------------------------------
// Fused attention: one block = (b, h, 64 q-rows), 16 k-tiles of 64.
// Rel bias Gq/Gk via MFMA (unconditional loop, R5-proven schedule), stored
// in stride-64 XOR8-swizzled arrays: elem(r,c) = [r*64 + (c ^ ((r&7)<<3))]
// -> ~2-way banks on both the b32 writes and the u16 diagonal gather.
// V from pre-transposed global Vt; dist pre-converted bf16, circular window.
// Fixed-max exp2 softmax.
// ---------------------------------------------------------------------------
__global__ __launch_bounds__(256) void attn(
    const u16* __restrict__ Q, const u16* __restrict__ Kv,
    const u16* __restrict__ Vt, const u16* __restrict__ distb,
    u16* __restrict__ ctx) {
  __shared__ u16 sQ[64][72];
  __shared__ u16 sK[64][72];      // probs overlay after barrier B
  __shared__ u16 sVt[64][72];     // V^T [d][r]
  __shared__ u16 sP[128][72];     // dist window, circular
  __shared__ u16 sGq[128 * 64];   // Gq[c][rl], XOR8-swizzled cols
  __shared__ u16 sGk[128 * 64];   // Gk[c][cl], XOR8-swizzled cols

  const int tid = threadIdx.x;
  const int lane = tid & 63, w = tid >> 6;
  const int quad = lane >> 4, lb = lane & 15;
  const int bh = blockIdx.y, b = bh >> 4, h = bh & 15;
  const int q0 = blockIdx.x << 6;
  const int S = 1024, E = 1024;
  const u16* Qb = Q  + (size_t)(b * S) * E + h * 64;
  const u16* Kb = Kv + (size_t)(b * S) * E + h * 64;
  const u16* Vtb = Vt + (size_t)bh * 64 * 1024;

  for (int ch = tid; ch < 512; ch += 256) {
    int r = ch >> 3, c8 = (ch & 7) << 3;
    *(i32x4*)&sQ[r][c8] = *(const i32x4*)&Qb[(size_t)(q0 + r) * E + c8];
  }
  __syncthreads();

  const int row = 16 * w + lb;
  bf16x8 aq0 = ldb8(&sQ[row][quad * 8]);
  bf16x8 aq1 = ldb8(&sQ[row][32 + quad * 8]);

  f32x4 accO[4] = {};
  float l_i[4] = {0.f, 0.f, 0.f, 0.f};
  const float C2 = 0.125f * 1.44269504f;

  for (int kt = 0; kt < 16; kt++) {
    const int r0 = kt << 6;
    const int xorv = (kt & 1) << 6;
    // stage K tile
    for (int ch = tid; ch < 512; ch += 256) {
      int r = ch >> 3, c8 = (ch & 7) << 3;
      *(i32x4*)&sK[r][c8] = *(const i32x4*)&Kb[(size_t)(r0 + r) * E + c8];
    }
    // stage V^T tile: direct b128 copy
    for (int ch = tid; ch < 512; ch += 256) {
      int r = ch >> 3, c8 = (ch & 7) << 3;
      *(i32x4*)&sVt[r][c8] = *(const i32x4*)&Vtb[(size_t)r * 1024 + r0 + c8];
    }
    // stage dist window (bf16, circular): kt=0 all 128 rows, else 64 new
    const int dbase = q0 - r0 + 960;
    if (kt == 0) {
      for (int ch = tid; ch < 1024; ch += 256) {
        int p = ch >> 3, c8 = (ch & 7) << 3;
        int g = dbase + p;
        if (g > 2046) g = 2046;
        *(i32x4*)&sP[p][c8] = *(const i32x4*)&distb[(size_t)g * 64 + c8];
      }
    } else {
      for (int ch = tid; ch < 512; ch += 256) {
        int p = ch >> 3, c8 = (ch & 7) << 3;
        int g = dbase + p;
        *(i32x4*)&sP[p ^ xorv][c8] = *(const i32x4*)&distb[(size_t)g * 64 + c8];
      }
    }
    __syncthreads();  // barrier A

    // --- QK^T ---
    f32x4 accS[4] = {};
#pragma unroll
    for (int t = 0; t < 4; t++) {
      int n = 16 * t + lb;
      bf16x8 b0 = ldb8(&sK[n][quad * 8]);
      bf16x8 b1 = ldb8(&sK[n][32 + quad * 8]);
      accS[t] = MFMA16(aq0, b0, accS[t]);
      accS[t] = MFMA16(aq1, b1, accS[t]);
    }
    // --- rel-bias GEMMs (unconditional; G rows = logical window index) ---
    bf16x8 ak0 = ldb8(&sK[row][quad * 8]);
    bf16x8 ak1 = ldb8(&sK[row][32 + quad * 8]);
#pragma unroll
    for (int u = 0; u < 8; u++) {
      int prow = (16 * u + lb) ^ xorv;  // physical sP row
      bf16x8 p0 = ldb8(&sP[prow][quad * 8]);
      bf16x8 p1 = ldb8(&sP[prow][32 + quad * 8]);
      f32x4 gq = {}, gk = {};
      gq = MFMA16(aq0, p0, gq); gq = MFMA16(aq1, p1, gq);
      gk = MFMA16(ak0, p0, gk); gk = MFMA16(ak1, p1, gk);
      int grow = 16 * u + lb;                       // logical window col
      int cswz = (16 * w + 4 * quad) ^ ((grow & 7) << 3);
      u16* gqb = &sGq[grow * 64 + cswz];
      u16* gkb = &sGk[grow * 64 + cswz];
      *(u32*)gqb = cvt2(gq[0], gq[1]);
      *(u32*)(gqb + 2) = cvt2(gq[2], gq[3]);
      *(u32*)gkb = cvt2(gk[0], gk[1]);
      *(u32*)(gkb + 2) = cvt2(gk[2], gk[3]);
    }
    __syncthreads();  // barrier B (G read cross-wave; sK dead after this)

    // --- bias gather + fixed-max softmax (exp2 domain) ---
    float pr[4][4], rsum[4] = {0.f, 0.f, 0.f, 0.f};
#pragma unroll
    for (int t = 0; t < 4; t++) {
#pragma unroll
      for (int i = 0; i < 4; i++) {
        int rl = 16 * w + quad * 4 + i;
        int cl = 16 * t + lb;
        int c = rl - cl + 63;           // window col 0..126
        int sw8 = (c & 7) << 3;
        float s = accS[t][i] + b2f(sGq[(c << 6) | (rl ^ sw8)]) +
                  b2f(sGk[(c << 6) | (cl ^ sw8)]);
        float e = fexp2(s * C2);
        pr[t][i] = e;
        rsum[i] += e;
      }
    }
#pragma unroll
    for (int i = 0; i < 4; i++) l_i[i] += rsum16(rsum[i]);

    // probs -> sK overlay (own-wave rows only)
#pragma unroll
    for (int t = 0; t < 4; t++)
#pragma unroll
      for (int i = 0; i < 4; i++)
        sK[16 * w + quad * 4 + i][16 * t + lb] = f2b(pr[t][i]);

    // --- PV ---
    bf16x8 ap0 = ldb8(&sK[row][quad * 8]);
    bf16x8 ap1 = ldb8(&sK[row][32 + quad * 8]);
#pragma unroll
    for (int t = 0; t < 4; t++) {
      int n = 16 * t + lb;
      bf16x8 v0 = ldb8(&sVt[n][quad * 8]);
      bf16x8 v1 = ldb8(&sVt[n][32 + quad * 8]);
      accO[t] = MFMA16(ap0, v0, accO[t]);
      accO[t] = MFMA16(ap1, v1, accO[t]);
    }
    __syncthreads();  // barrier C
  }

  u16* Cb = ctx + (size_t)(b * S) * E + h * 64;
#pragma unroll
  for (int t = 0; t < 4; t++)
#pragma unroll
    for (int i = 0; i < 4; i++) {
      int rl = 16 * w + quad * 4 + i;
      Cb[(size_t)(q0 + rl) * E + 16 * t + lb] = f2b(accO[t][i] / l_i[i]);
    }
}

// ---------------------------------------------------------------------------
__global__ __launch_bounds__(256) void lnorm(
    const float* __restrict__ Hp, const float* __restrict__ gamma,
    const float* __restrict__ beta, float* __restrict__ out) {
  __shared__ float red[8];
  const int rowb = blockIdx.x, tid = threadIdx.x;
  const float* hr = Hp + (size_t)rowb * 1024;
  f32x4 v = *(const f32x4*)&hr[tid * 4];
  float s = v.x + v.y + v.z + v.w;
  float q = v.x * v.x + v.y * v.y + v.z * v.z + v.w * v.w;
#pragma unroll
  for (int d = 1; d < 64; d <<= 1) {
    s += __shfl_xor(s, d, 64);
    q += __shfl_xor(q, d, 64);
  }
  int w = tid >> 6, lane = tid & 63;
  if (lane == 0) { red[w] = s; red[4 + w] = q; }
  __syncthreads();
  s = red[0] + red[1] + red[2] + red[3];
  q = red[4] + red[5] + red[6] + red[7];
  float mu = s * (1.f / 1024.f);
  float var = q * (1.f / 1024.f) - mu * mu;
  float rstd = rsqrtf(var + 1e-12f);
  float* orow = out + (size_t)rowb * 1024;
  f32x4 o;
#pragma unroll
  for (int j = 0; j < 4; j++) {
    int c = tid * 4 + j;
    o[j] = (v[j] - mu) * rstd * gamma[c] + beta[c];
  }
  *(f32x4*)&orow[tid * 4] = o;
}

// ---------------------------------------------------------------------------
extern "C" void kernel_launch(void* const* d_in, const int* in_sizes, int n_in,
                              void* d_out, int out_size, void* d_ws,
                              size_t ws_size, hipStream_t stream) {
  const float* X    = (const float*)d_in[0];
  const float* Wq   = (const float*)d_in[1];
  const float* bq   = (const float*)d_in[2];
  const float* Wk   = (const float*)d_in[3];
  const float* bk   = (const float*)d_in[4];
  const float* Wv   = (const float*)d_in[5];
  const float* bv   = (const float*)d_in[6];
  const float* dist = (const float*)d_in[7];
  const float* Wo   = (const float*)d_in[8];
  const float* bo   = (const float*)d_in[9];
  const float* gam  = (const float*)d_in[10];
  const float* bet  = (const float*)d_in[11];

  const size_t NE = (size_t)8192 * 1024;
  char* ws = (char*)d_ws;
  u16* Qw = (u16*)(ws);
  u16* Kw = (u16*)(ws + 2 * NE);
  u16* Vw = (u16*)(ws + 4 * NE);
  u16* Cw = (u16*)(ws + 6 * NE);
  float* Hp = (float*)ws;  // fp32 pre-LN, overlays dead Q+K

  // d_out (32 MiB fp32) as scratch until lnorm overwrites it.
  char* ob = (char*)d_out;
  u16* Wtq = (u16*)(ob);
  u16* Wtk = (u16*)(ob + (2u << 20));
  u16* Wtv = (u16*)(ob + (4u << 20));
  u16* Wto = (u16*)(ob + (6u << 20));
  u16* Xb  = (u16*)(ob + (8u << 20));
  u16* Vtg = (u16*)(ob + (8u << 20));   // overlays Xb (disjoint lifetime)
  u16* distb = (u16*)(ob + (26u << 20));

  dim3 bb(256);
  dim3 gw(16, 16);
  convWt<<<gw, bb, 0, stream>>>(Wq, Wtq);
  convWt<<<gw, bb, 0, stream>>>(Wk, Wtk);
  convWt<<<gw, bb, 0, stream>>>(Wv, Wtv);
  convWt<<<gw, bb, 0, stream>>>(Wo, Wto);
  convX<<<dim3(4096), bb, 0, stream>>>(X, Xb);
  convD<<<dim3(64), bb, 0, stream>>>(dist, distb);

  dim3 gg(8, 64);
  gemm_bb<0, 0><<<gg, bb, 0, stream>>>(Xb, Wtq, bq, nullptr, nullptr, Qw, 8192, 1024, 1024);
  gemm_bb<0, 0><<<gg, bb, 0, stream>>>(Xb, Wtk, bk, nullptr, nullptr, Kw, 8192, 1024, 1024);
  gemm_bb<0, 0><<<gg, bb, 0, stream>>>(Xb, Wtv, bv, nullptr, nullptr, Vw, 8192, 1024, 1024);
  transV<<<dim3(16, 128), bb, 0, stream>>>(Vw, Vtg);
  attn<<<dim3(16, 128), bb, 0, stream>>>(Qw, Kw, Vtg, distb, Cw);
  gemm_bb<1, 1><<<gg, bb, 0, stream>>>(Cw, Wto, bo, X, Hp, nullptr, 8192, 1024, 1024);
  lnorm<<<dim3(8192), bb, 0, stream>>>(Hp, gam, bet, (float*)d_out);
}